// Round 7
// baseline (1292.351 us; speedup 1.0000x reference)
//
#include <hip/hip_runtime.h>
#include <hip/hip_bf16.h>

#define T_ 32
#define B_ 16
#define I_ 512
#define H_ 512
#define OFF_ 441
#define NR_ 71           // I_ - OFF_
#define NC_ 2556         // NR_*(NR_+1)/2
#define G4_ (4*NC_)      // 10224
#define NCP_ 2560        // K padded
#define NPR_ 10240       // padded gate-permuted row count
#define NTIL_ 640        // NPR_/16
#define NSF_ 8           // fallback K-split
#define KCHF_ 320        // fallback chunk

typedef __attribute__((ext_vector_type(8))) short bf16x8;
typedef __attribute__((ext_vector_type(4))) float f32x4;

__device__ __forceinline__ ushort bfc(float f) {
    __hip_bfloat16 h = __float2bfloat16(f);
    return *(ushort*)&h;
}
__device__ __forceinline__ float b2f(ushort u) {
    return __uint_as_float((uint)u << 16);
}
__device__ __forceinline__ float sigf(float x) { return 1.f / (1.f + expf(-x)); }

__global__ void k_zero(float* __restrict__ p, int n) {
    int i = blockIdx.x * 256 + threadIdx.x;
    if (i < n) p[i] = 0.f;
}

// x fp32 [512][512] -> bf16 same layout
__global__ void k_cvt_x(const float* __restrict__ x, ushort* __restrict__ xb) {
    int i = blockIdx.x * 256 + threadIdx.x;   // float4 slot, 65536 total
    float4 v = ((const float4*)x)[i];
    ushort4 o; o.x = bfc(v.x); o.y = bfc(v.y); o.z = bfc(v.z); o.w = bfc(v.w);
    ((ushort4*)xb)[i] = o;
}

// Wih[l] fp32 [G4][512] -> bf16 gate-permuted [NPR][512]; row n' = 4*jc+q <- q*NC+jc
__global__ void k_cvt_w512p(const float* __restrict__ W0, const float* __restrict__ W1,
                            ushort* __restrict__ dst) {
    int l = blockIdx.z;
    const float* src = l ? W1 : W0;
    size_t idx = (size_t)blockIdx.x * 256 + threadIdx.x;   // over NPR*128
    int np = (int)(idx >> 7), kq = (int)(idx & 127);
    ushort4 o; o.x = 0; o.y = 0; o.z = 0; o.w = 0;
    int jc = np >> 2, q = np & 3;
    if (jc < NC_) {
        float4 v = *(const float4*)(src + ((size_t)q * NC_ + jc) * I_ + kq * 4);
        o.x = bfc(v.x); o.y = bfc(v.y); o.z = bfc(v.z); o.w = bfc(v.w);
    }
    ((ushort4*)(dst + ((size_t)l * NPR_ + np) * I_))[kq] = o;
}

// Whh[l] fp32 [G4][2556] -> bf16 gate-permuted K-padded [NPR][2560]
__global__ void k_cvt_whhp(const float* __restrict__ W0, const float* __restrict__ W1,
                           ushort* __restrict__ dst) {
    int l = blockIdx.z;
    const float* src = l ? W1 : W0;
    size_t idx = (size_t)blockIdx.x * 256 + threadIdx.x;   // over NPR*640
    int np = (int)(idx / 640), s = (int)(idx - (size_t)np * 640);
    ushort4 o; o.x = 0; o.y = 0; o.z = 0; o.w = 0;
    int jc = np >> 2, q = np & 3;
    if (jc < NC_ && s < 639) {
        float4 v = *(const float4*)(src + ((size_t)q * NC_ + jc) * NC_ + s * 4);
        o.x = bfc(v.x); o.y = bfc(v.y); o.z = bfc(v.z); o.w = bfc(v.w);
    }
    ((ushort4*)(dst + ((size_t)l * NPR_ + np) * NCP_))[s] = o;
}

// MFMA input GEMM -> preT[l][n'][m] bf16, m = t*16+b; permuted bias added
__global__ __launch_bounds__(256) void k_gih_mfma(const ushort* __restrict__ Xbf,
        const ushort* __restrict__ Wp,
        const float* __restrict__ b0, const float* __restrict__ b1,
        ushort* __restrict__ preT) {
    const int l = blockIdx.z;
    const float* bb = l ? b1 : b0;
    const int wid = threadIdx.x >> 6, lane = threadIdx.x & 63;
    const int nt = blockIdx.x * 4 + wid;
    __shared__ ushort lds_a[32 * 64 * 8];   // 32 KB, frag-linear
    const int srow = lane & 15, skq = (lane >> 4) * 8;
    const ushort* wp = Wp + ((size_t)l * NPR_ + nt * 16 + srow) * I_ + skq;
    f32x4 acc[32];
    #pragma unroll
    for (int mt = 0; mt < 32; ++mt) acc[mt] = (f32x4){0.f, 0.f, 0.f, 0.f};
    for (int ks = 0; ks < 16; ++ks) {
        #pragma unroll
        for (int i = 0; i < 8; ++i) {
            int mt = wid * 8 + i;
            bf16x8 xv = *(const bf16x8*)(Xbf + (size_t)(mt * 16 + srow) * I_ + ks * 32 + skq);
            *(bf16x8*)(lds_a + (mt * 64 + lane) * 8) = xv;
        }
        bf16x8 b = *(const bf16x8*)(wp + ks * 32);
        __syncthreads();
        #pragma unroll
        for (int mt = 0; mt < 32; ++mt) {
            bf16x8 a = *(const bf16x8*)(lds_a + (mt * 64 + lane) * 8);
            acc[mt] = __builtin_amdgcn_mfma_f32_16x16x32_bf16(a, b, acc[mt], 0, 0, 0);
        }
        __syncthreads();
    }
    const int n = nt * 16 + srow;
    const float bv = (n < G4_) ? bb[(size_t)(n & 3) * NC_ + (n >> 2)] : 0.f;
    const int r0 = (lane >> 4) * 4;
    ushort* po = preT + ((size_t)l * NPR_ + n) * 512;
    #pragma unroll
    for (int mt = 0; mt < 32; ++mt) {
        ushort4 o;
        o.x = bfc(acc[mt][0] + bv); o.y = bfc(acc[mt][1] + bv);
        o.z = bfc(acc[mt][2] + bv); o.w = bfc(acc[mt][3] + bv);
        *(ushort4*)(po + mt * 16 + r0) = o;
    }
}

// Fused recurrent step v2: 4 waves/block, K split 4x640 across waves, LDS reduce.
__global__ __launch_bounds__(256, 5) void k_step(const ushort* __restrict__ Wp,
        const ushort* __restrict__ preT,
        const ushort* __restrict__ hbf_in, ushort* __restrict__ hbf_out,
        float* __restrict__ cst, float* __restrict__ hbuf,
        const float* __restrict__ scal_ih, const float* __restrict__ scal_hh,
        int t) {
    const int l = blockIdx.z;
    const int nt = blockIdx.x;
    const int tid = threadIdx.x;
    const int w = tid >> 6, lane = tid & 63;
    const int col = lane & 15;
    const int kq = (lane >> 4) * 8;
    const int kbase = w * 640;
    const ushort* wp = Wp + ((size_t)l * NPR_ + nt * 16 + col) * NCP_ + kbase + kq;
    const ushort* hp = hbf_in + ((size_t)l * B_ + col) * NCP_ + kbase + kq;
    f32x4 acc = {0.f, 0.f, 0.f, 0.f};
    #pragma unroll 5
    for (int ks = 0; ks < 20; ++ks) {
        bf16x8 a = *(const bf16x8*)(hp + ks * 32);
        bf16x8 b = *(const bf16x8*)(wp + ks * 32);
        acc = __builtin_amdgcn_mfma_f32_16x16x32_bf16(a, b, acc, 0, 0, 0);
    }
    __shared__ float gl[4][16][17];
    const int m0 = (lane >> 4) * 4;   // batch base of this lane's 4 acc rows
    if (w == 0) {
        const ushort4 p4 = *(const ushort4*)(preT +
            ((size_t)l * NPR_ + nt * 16 + col) * 512 + t * 16 + m0);
        gl[0][col][m0 + 0] = acc[0] + b2f(p4.x);
        gl[0][col][m0 + 1] = acc[1] + b2f(p4.y);
        gl[0][col][m0 + 2] = acc[2] + b2f(p4.z);
        gl[0][col][m0 + 3] = acc[3] + b2f(p4.w);
    } else {
        gl[w][col][m0 + 0] = acc[0];
        gl[w][col][m0 + 1] = acc[1];
        gl[w][col][m0 + 2] = acc[2];
        gl[w][col][m0 + 3] = acc[3];
    }
    __syncthreads();
    // gate pass on first wave: thread -> (b = tid&15, jq = tid>>4)
    if (tid < 64) {
        const int b = tid & 15, jq = tid >> 4;
        const int jc = nt * 4 + jq;
        if (jc < NC_) {
            float g[4];
            #pragma unroll
            for (int q = 0; q < 4; ++q)
                g[q] = gl[0][jq * 4 + q][b] + gl[1][jq * 4 + q][b]
                     + gl[2][jq * 4 + q][b] + gl[3][jq * 4 + q][b];
            float* cp = cst + ((size_t)l * NC_ + jc) * B_ + b;
            float ci = *cp;
            float cn = sigf(g[1]) * ci + sigf(g[0]) * tanhf(g[2]);
            float hn = sigf(g[3]) * tanhf(cn);
            *cp = cn;
            hbf_out[((size_t)l * B_ + b) * NCP_ + jc] = bfc(hn);
            float sc = (l ? scal_hh : scal_ih)[jc];
            hbuf[(((size_t)l * T_ + t) * B_ + b) * NC_ + jc] = hn * sc;
        }
    }
}

// ---------------- fallback path (small workspace) ----------------
__global__ __launch_bounds__(256) void k_gih(const float* __restrict__ X,
        const float* __restrict__ W0, const float* __restrict__ b0,
        const float* __restrict__ W1, const float* __restrict__ b1,
        float* __restrict__ pre) {
    const int l = blockIdx.z;
    const float* W = l ? W1 : W0;
    const float* bb = l ? b1 : b0;
    float* out = pre + (size_t)l * T_ * B_ * G4_;
    const int m0 = blockIdx.x * 128;
    const int n0 = blockIdx.y * 64;
    __shared__ float Xs[16][132];
    __shared__ float Ws[16][68];
    const int tid = threadIdx.x;
    const int tx = tid & 15, ty = tid >> 4;
    float acc[8][4] = {};
    for (int kt = 0; kt < I_; kt += 16) {
        #pragma unroll
        for (int i = 0; i < 2; ++i) {
            int idx = tid + i * 256;
            int kqq = idx >> 7, m = idx & 127;
            float4 xv = *(const float4*)&X[(size_t)(m0 + m) * I_ + kt + kqq * 4];
            Xs[kqq * 4 + 0][m] = xv.x; Xs[kqq * 4 + 1][m] = xv.y;
            Xs[kqq * 4 + 2][m] = xv.z; Xs[kqq * 4 + 3][m] = xv.w;
        }
        {
            int n = tid >> 2, kqq = tid & 3;
            float4 wv = make_float4(0.f, 0.f, 0.f, 0.f);
            if (n0 + n < G4_)
                wv = *(const float4*)&W[(size_t)(n0 + n) * I_ + kt + kqq * 4];
            Ws[kqq * 4 + 0][n] = wv.x; Ws[kqq * 4 + 1][n] = wv.y;
            Ws[kqq * 4 + 2][n] = wv.z; Ws[kqq * 4 + 3][n] = wv.w;
        }
        __syncthreads();
        #pragma unroll
        for (int kk = 0; kk < 16; ++kk) {
            float a[8], bv[4];
            #pragma unroll
            for (int p = 0; p < 8; ++p) a[p] = Xs[kk][ty * 8 + p];
            #pragma unroll
            for (int q = 0; q < 4; ++q) bv[q] = Ws[kk][tx * 4 + q];
            #pragma unroll
            for (int p = 0; p < 8; ++p)
                #pragma unroll
                for (int q = 0; q < 4; ++q) acc[p][q] += a[p] * bv[q];
        }
        __syncthreads();
    }
    #pragma unroll
    for (int p = 0; p < 8; ++p) {
        int m = m0 + ty * 8 + p;
        #pragma unroll
        for (int q = 0; q < 4; ++q) {
            int n = n0 + tx * 4 + q;
            if (n < G4_) out[(size_t)m * G4_ + n] = acc[p][q] + bb[n];
        }
    }
}

__global__ __launch_bounds__(256) void k_rec_f(const float* __restrict__ Wt0,
        const float* __restrict__ Wt1,
        const float* __restrict__ hst, float* __restrict__ part) {
    int j = blockIdx.x * 256 + threadIdx.x;
    int s = blockIdx.y, l = blockIdx.z;
    if (j >= G4_) return;
    const float* wmat = l ? Wt1 : Wt0;
    const float* h = hst + (size_t)l * B_ * NC_;
    int k0 = s * KCHF_, k1 = (NC_ < k0 + KCHF_) ? NC_ : (k0 + KCHF_);
    float acc[B_] = {};
    #pragma unroll 4
    for (int k = k0; k < k1; ++k) {
        float w = wmat[(size_t)j * NC_ + k];
        #pragma unroll
        for (int b = 0; b < B_; ++b) acc[b] += h[b * NC_ + k] * w;
    }
    float* po = part + ((size_t)(l * NSF_ + s) * B_) * G4_ + j;
    #pragma unroll
    for (int b = 0; b < B_; ++b) po[(size_t)b * G4_] = acc[b];
}

__global__ void k_gate_f(const float* __restrict__ part, const float* __restrict__ pre,
                         const float* __restrict__ scal_ih, const float* __restrict__ scal_hh,
                         float* __restrict__ cst, float* __restrict__ hst,
                         float* __restrict__ hbuf, int t) {
    int idx = blockIdx.x * 256 + threadIdx.x;
    if (idx >= 2 * B_ * NC_) return;
    int l = idx / (B_ * NC_);
    int r = idx - l * (B_ * NC_);
    int b = r / NC_;
    int jc = r - b * NC_;
    float g[4];
    #pragma unroll
    for (int q = 0; q < 4; ++q) {
        float s = pre[(((size_t)l * T_ + t) * B_ + b) * G4_ + q * NC_ + jc];
        #pragma unroll
        for (int sp = 0; sp < NSF_; ++sp)
            s += part[((size_t)(l * NSF_ + sp) * B_ + b) * G4_ + q * NC_ + jc];
        g[q] = s;
    }
    float ci = cst[idx];
    float cn = sigf(g[1]) * ci + sigf(g[0]) * tanhf(g[2]);
    float hn = sigf(g[3]) * tanhf(cn);
    cst[idx] = cn;
    hst[idx] = hn;
    float sc = (l ? scal_hh : scal_ih)[jc];
    hbuf[(((size_t)l * T_ + t) * B_ + b) * NC_ + jc] = hn * sc;
}
// ---------------- end fallback ----------------

// Bt[k][h] = idct_hid[h][k] for k < 71
__global__ void k_bt(const float* __restrict__ Bh, float* __restrict__ Bt) {
    int idx = blockIdx.x * 256 + threadIdx.x;
    if (idx < NR_ * H_) {
        int k = idx / H_, h = idx - k * H_;
        Bt[idx] = Bh[(size_t)h * H_ + k];
    }
}

// yih[t,b,h] = sum_k Bt[k,h] * v[k]; coeffs pre-scaled in hbuf
__global__ __launch_bounds__(256) void k_yih(const float* __restrict__ x,
        const float* __restrict__ Ain, const float* __restrict__ Bt,
        const float* __restrict__ hbuf0, float* __restrict__ yih) {
    __shared__ float xl[I_];
    __shared__ float u[NR_];
    __shared__ float v[NR_];
    int tb = blockIdx.x;
    int tid = threadIdx.x;
    xl[tid] = x[(size_t)tb * I_ + tid];
    xl[tid + 256] = x[(size_t)tb * I_ + tid + 256];
    __syncthreads();
    if (tid < NR_) {
        float a = 0.f;
        for (int jj = 0; jj < I_; ++jj) a += Ain[(size_t)jj * I_ + tid] * xl[jj];
        u[tid] = a;
    }
    __syncthreads();
    if (tid < NR_) {
        int k = tid;
        int start = k * NR_ - (k * (k - 1)) / 2;
        int cnt = NR_ - k;
        const float* cf = hbuf0 + (size_t)tb * NC_;
        float a = 0.f;
        for (int m = 0; m < cnt; ++m) a += cf[start + m] * u[cnt - 1 - m];
        v[k] = a;
    }
    __syncthreads();
    for (int h = tid; h < H_; h += 256) {
        float a = 0.f;
        #pragma unroll
        for (int k = 0; k < NR_; ++k) a += Bt[(size_t)k * H_ + h] * v[k];
        yih[(size_t)tb * H_ + h] = a;
    }
}

// sequential phase-2 v3: register-batched LDS loads, yih prefetch, dbuf h, 3 barriers
#define BTP_ 520
__global__ __launch_bounds__(576, 3) void k_seq(const float* __restrict__ yih,
        const float* __restrict__ Bt, const float* __restrict__ cf_all,
        const float* __restrict__ bias, float* __restrict__ out) {
    __shared__ __align__(16) float bt[NR_ * BTP_];   // 147.7 KB
    __shared__ __align__(16) float hl[2][H_];
    __shared__ float u[NR_ + 1];
    __shared__ __align__(16) float v[NR_ + 1];
    const int b = blockIdx.x, tid = threadIdx.x;
    for (int i = tid; i < NR_ * H_; i += 576)
        bt[(i >> 9) * BTP_ + (i & 511)] = Bt[i];
    for (int i = tid; i < H_; i += 576) hl[0][i] = 0.f;
    if (tid == 0) { u[NR_] = 0.f; v[NR_] = 0.f; }
    const float bvs = (tid < H_) ? bias[tid] : 0.f;
    const int g = tid >> 3, lane = tid & 7;
    int start = 0, cnt = 0;
    if (g < NR_) { start = g * NR_ - (g * (g - 1)) / 2; cnt = NR_ - g; }
    int p = 0;
    __syncthreads();
    for (int t = 0; t < T_; ++t) {
        // prefetch global operands for this step (hidden under u/v phases)
        float yv = 0.f;
        if (tid < H_) yv = yih[((size_t)t * B_ + b) * H_ + tid];
        float cfv[9];
        if (g < NR_) {
            const float* cf = cf_all + ((size_t)t * B_ + b) * NC_ + start;
            #pragma unroll
            for (int mi = 0; mi < 9; ++mi) {
                int m = mi * 8 + lane;
                cfv[mi] = cf[m < cnt ? m : (cnt - 1)];
            }
        }
        // u[g] = sum_j bt[g][j]*h[j] — batch ALL loads into regs, then 4 fma chains
        if (g < NR_) {
            const float* bp = bt + g * BTP_ + lane * 4;
            const float* hp = hl[p] + lane * 4;
            float4 bq[16], hq[16];
            #pragma unroll
            for (int m = 0; m < 16; ++m) bq[m] = *(const float4*)(bp + m * 32);
            #pragma unroll
            for (int m = 0; m < 16; ++m) hq[m] = *(const float4*)(hp + m * 32);
            float a0 = 0.f, a1 = 0.f, a2 = 0.f, a3 = 0.f;
            #pragma unroll
            for (int m = 0; m < 16; ++m) {
                a0 += bq[m].x * hq[m].x;
                a1 += bq[m].y * hq[m].y;
                a2 += bq[m].z * hq[m].z;
                a3 += bq[m].w * hq[m].w;
            }
            float a = (a0 + a1) + (a2 + a3);
            a += __shfl_xor(a, 1); a += __shfl_xor(a, 2); a += __shfl_xor(a, 4);
            if (lane == 0) u[g] = a;
        }
        __syncthreads();
        // v[g] = triangular combine with prefetched coeffs
        if (g < NR_) {
            float a = 0.f;
            #pragma unroll
            for (int mi = 0; mi < 9; ++mi) {
                int m = mi * 8 + lane;
                a += (m < cnt) ? cfv[mi] * u[cnt - 1 - m] : 0.f;
            }
            a += __shfl_xor(a, 1); a += __shfl_xor(a, 2); a += __shfl_xor(a, 4);
            if (lane == 0) v[g] = a;
        }
        __syncthreads();
        // h[tid] = tanh(yih + Bt^T v + bias); 4 chains
        if (tid < H_) {
            float4 vv[18];
            #pragma unroll
            for (int q = 0; q < 18; ++q) vv[q] = *(const float4*)(v + q * 4);
            float a0 = 0.f, a1 = 0.f, a2 = 0.f, a3 = 0.f;
            #pragma unroll
            for (int k = 0; k < 68; k += 4) {
                a0 += bt[(k + 0) * BTP_ + tid] * ((const float*)vv)[k + 0];
                a1 += bt[(k + 1) * BTP_ + tid] * ((const float*)vv)[k + 1];
                a2 += bt[(k + 2) * BTP_ + tid] * ((const float*)vv)[k + 2];
                a3 += bt[(k + 3) * BTP_ + tid] * ((const float*)vv)[k + 3];
            }
            a0 += bt[68 * BTP_ + tid] * ((const float*)vv)[68];
            a1 += bt[69 * BTP_ + tid] * ((const float*)vv)[69];
            a2 += bt[70 * BTP_ + tid] * ((const float*)vv)[70];
            float hv = tanhf(yv + (a0 + a1) + (a2 + a3) + bvs);
            out[((size_t)t * B_ + b) * H_ + tid] = hv;
            hl[p ^ 1][tid] = hv;
        }
        __syncthreads();
        p ^= 1;
    }
}

extern "C" void kernel_launch(void* const* d_in, const int* in_sizes, int n_in,
                              void* d_out, int out_size, void* d_ws, size_t ws_size,
                              hipStream_t stream) {
    const float* x        = (const float*)d_in[0];
    const float* wih_ih   = (const float*)d_in[1];
    const float* wih_hh   = (const float*)d_in[2];
    const float* wih_b    = (const float*)d_in[3];
    const float* whh_ih   = (const float*)d_in[4];
    const float* whh_hh   = (const float*)d_in[5];
    const float* whh_b    = (const float*)d_in[6];
    const float* scal_ih  = (const float*)d_in[7];
    const float* scal_hh  = (const float*)d_in[8];
    const float* bias     = (const float*)d_in[9];
    const float* idct_in  = (const float*)d_in[10];
    const float* idct_hid = (const float*)d_in[11];
    float* out = (float*)d_out;

    const size_t WP_B   = (size_t)2 * NPR_ * NCP_ * 2;    // 104,857,600
    const size_t PRET_B = (size_t)2 * NPR_ * 512 * 2;     //  20,971,520
    const size_t HBUF_B = (size_t)2 * T_ * B_ * NC_ * 4;  //  10,469,376
    const size_t HBF_B  = (size_t)2 * 2 * B_ * NCP_ * 2;  //     655,360 (ping-pong)
    const size_t CST_B  = (size_t)2 * NC_ * B_ * 4;       //     327,168
    const size_t YIH_B  = (size_t)T_ * B_ * H_ * 4;
    const size_t BT_B   = (size_t)NR_ * H_ * 4;
    const size_t need_mfma = WP_B + PRET_B + HBUF_B + HBF_B + CST_B + YIH_B + BT_B + 4096;

    char* ws = (char*)d_ws;
    size_t off = 0;
    auto alloc = [&](size_t bytes) -> void* {
        void* p = (void*)(ws + off);
        off += (bytes + 255) & ~(size_t)255;
        return p;
    };

    if (ws_size >= need_mfma) {
        ushort* Wp   = (ushort*)alloc(WP_B);
        ushort* preT = (ushort*)alloc(PRET_B);
        float*  hbuf = (float*)alloc(HBUF_B);
        ushort* hbf  = (ushort*)alloc(HBF_B);
        float*  cst  = (float*)alloc(CST_B);
        float*  yih  = (float*)alloc(YIH_B);
        float*  Bt   = (float*)alloc(BT_B);
        // aliases inside Wp region (dead before k_cvt_whhp runs)
        ushort* Wih_p = Wp;
        ushort* Xbf   = (ushort*)((char*)Wp + 21000192);

        {   // zero hbf (both buffers) + cst (contiguous allocs)
            int n = (int)((HBF_B + 256 + CST_B) / 4);
            hipLaunchKernelGGL(k_zero, dim3((n + 255) / 256), dim3(256), 0, stream,
                               (float*)hbf, n);
        }
        hipLaunchKernelGGL(k_cvt_x, dim3(256), dim3(256), 0, stream, x, Xbf);
        hipLaunchKernelGGL(k_cvt_w512p, dim3(NPR_ * 128 / 256, 1, 2), dim3(256), 0, stream,
                           wih_ih, whh_ih, Wih_p);
        hipLaunchKernelGGL(k_gih_mfma, dim3(160, 1, 2), dim3(256), 0, stream,
                           Xbf, Wih_p, wih_b, whh_b, preT);
        hipLaunchKernelGGL(k_cvt_whhp, dim3(NPR_ * 640 / 256, 1, 2), dim3(256), 0, stream,
                           wih_hh, whh_hh, Wp);

        const size_t HS = (size_t)2 * B_ * NCP_;   // ushorts per ping-pong buffer
        for (int t = 0; t < T_; ++t) {
            const ushort* hin  = hbf + (size_t)(t & 1) * HS;
            ushort*       hout = hbf + (size_t)((t & 1) ^ 1) * HS;
            hipLaunchKernelGGL(k_step, dim3(NTIL_, 1, 2), dim3(256), 0, stream,
                               Wp, preT, hin, hout, cst, hbuf, scal_ih, scal_hh, t);
        }

        hipLaunchKernelGGL(k_bt, dim3((NR_ * H_ + 255) / 256), dim3(256), 0, stream,
                           idct_hid, Bt);
        hipLaunchKernelGGL(k_yih, dim3(T_ * B_), dim3(256), 0, stream,
                           x, idct_in, Bt, hbuf, yih);
        hipLaunchKernelGGL(k_seq, dim3(B_), dim3(576), 0, stream,
                           yih, Bt, hbuf + (size_t)T_ * B_ * NC_, bias, out);
    } else {
        // fp32 fallback
        float* pre  = (float*)alloc((size_t)2 * T_ * B_ * G4_ * 4);
        float* part = (float*)alloc((size_t)2 * NSF_ * B_ * G4_ * 4);
        float* hbuf = (float*)alloc(HBUF_B);
        float* hst  = (float*)alloc((size_t)2 * B_ * NC_ * 4);
        float* cst  = (float*)alloc((size_t)2 * B_ * NC_ * 4);
        float* yih  = (float*)alloc(YIH_B);
        float* Bt   = (float*)alloc(BT_B);
        {
            int n = 4 * B_ * NC_;
            hipLaunchKernelGGL(k_zero, dim3((n + 255) / 256), dim3(256), 0, stream, hst, n);
        }
        hipLaunchKernelGGL(k_gih, dim3(4, 160, 2), dim3(256), 0, stream,
                           x, wih_ih, wih_b, whh_ih, whh_b, pre);
        for (int t = 0; t < T_; ++t) {
            hipLaunchKernelGGL(k_rec_f, dim3(40, NSF_, 2), dim3(256), 0, stream,
                               wih_hh, whh_hh, hst, part);
            hipLaunchKernelGGL(k_gate_f, dim3(320), dim3(256), 0, stream,
                               part, pre, scal_ih, scal_hh, cst, hst, hbuf, t);
        }
        hipLaunchKernelGGL(k_bt, dim3((NR_ * H_ + 255) / 256), dim3(256), 0, stream,
                           idct_hid, Bt);
        hipLaunchKernelGGL(k_yih, dim3(T_ * B_), dim3(256), 0, stream,
                           x, idct_in, Bt, hbuf, yih);
        hipLaunchKernelGGL(k_seq, dim3(B_), dim3(576), 0, stream,
                           yih, Bt, hbuf + (size_t)T_ * B_ * NC_, bias, out);
    }
}